// Round 2
// baseline (310.857 us; speedup 1.0000x reference)
//
#include <hip/hip_runtime.h>
#include <hip/hip_bf16.h>

typedef short short8 __attribute__((ext_vector_type(8)));
typedef float floatx4 __attribute__((ext_vector_type(4)));

static constexpr int BATCH = 8;
static constexpr int NN    = 10000;
static constexpr int EE    = 160000;
static constexpr int EE2   = EE + NN;
static constexpr int DD    = 128;
static constexpr float SLOPE = 0.2f;
static constexpr int CAP   = 256;
static constexpr long OUT_ELEMS = (long)BATCH * NN * DD;   // x_out elements before attn

__device__ inline float ldf(const void* p, long i, int f32) {
    return f32 ? ((const float*)p)[i]
               : __bfloat162float(((const __hip_bfloat16*)p)[i]);
}
__device__ inline int esrc(const int* ei, int e, int i64) { return i64 ? ei[2 * e] : ei[e]; }
__device__ inline int edst(const int* ei, int e, int i64) { return i64 ? ei[2 * (EE + e)] : ei[EE + e]; }
__device__ inline short bf16bits(float v) {
    __hip_bfloat16 b = __float2bfloat16(v);
    short s; __builtin_memcpy(&s, &b, 2); return s;
}

// flags[0] = floats are fp32; flags[1] = edge_index is int64
__global__ __launch_bounds__(256) void k_detect(const unsigned short* __restrict__ xu,
                                                const int* __restrict__ ei,
                                                int* __restrict__ flags) {
    __shared__ int cnt[2];
    if (threadIdx.x < 2) cnt[threadIdx.x] = 0;
    __syncthreads();
    int c1 = 0;
    for (int i = threadIdx.x; i < 32768; i += 256) {
        unsigned short u = xu[i];
        if ((u & 0x7F80u) == 0x7F80u) c1++;
    }
    int c2 = 0;
    if (threadIdx.x < 256 && ei[2 * threadIdx.x + 1] != 0) c2 = 1;
    if (c1) atomicAdd(&cnt[0], c1);
    if (c2) atomicAdd(&cnt[1], c2);
    __syncthreads();
    if (threadIdx.x == 0) { flags[0] = (cnt[0] > 0); flags[1] = (cnt[1] == 0); }
}

__global__ __launch_bounds__(64) void k_c(const void* __restrict__ We,
                                          const void* __restrict__ att_edge,
                                          const int* __restrict__ flags,
                                          float* __restrict__ cout) {
    int f32 = flags[0];
    int lane = threadIdx.x;
    float s = ldf(We, lane, f32)      * ldf(att_edge, lane, f32)
            + ldf(We, lane + 64, f32) * ldf(att_edge, lane + 64, f32);
    for (int o = 1; o < 64; o <<= 1) s += __shfl_xor(s, o, 64);
    if (lane == 0) *cout = s;
}

__global__ __launch_bounds__(256) void k_deg(const int* __restrict__ ei,
                                             const void* __restrict__ attr,
                                             const int* __restrict__ flags,
                                             int* __restrict__ deg, float* __restrict__ lsum) {
    int f32 = flags[0], i64 = flags[1];
    int e = blockIdx.x * 256 + threadIdx.x;
    if (e < EE) {
        int d = edst(ei, e, i64);
        atomicAdd(&deg[d], 1);
        atomicAdd(&lsum[d], ldf(attr, e, f32));
    }
}

template<int F32>
__device__ inline void gemm_core(const void* __restrict__ x, const void* __restrict__ W,
                                 long rows_base, int l15, int quad, floatx4 acc[8]) {
    short8 afr[4];
    if (F32) {
        const float* xr = (const float*)x + (rows_base + l15) * DD;
        #pragma unroll
        for (int kk = 0; kk < 4; kk++) {
            const float* p = xr + kk * 32 + quad * 8;
            short8 a;
            #pragma unroll
            for (int j = 0; j < 8; j++) a[j] = bf16bits(p[j]);
            afr[kk] = a;
        }
    } else {
        const short* xr = (const short*)x + (rows_base + l15) * DD;
        #pragma unroll
        for (int kk = 0; kk < 4; kk++)
            afr[kk] = *(const short8*)(xr + kk * 32 + quad * 8);
    }
    #pragma unroll
    for (int jt = 0; jt < 8; jt++) {
        #pragma unroll
        for (int kk = 0; kk < 4; kk++) {
            short8 bfr;
            if (F32) {
                const float* p = (const float*)W + (jt * 16 + l15) * DD + kk * 32 + quad * 8;
                #pragma unroll
                for (int j = 0; j < 8; j++) bfr[j] = bf16bits(p[j]);
            } else {
                bfr = *(const short8*)((const short*)W + (jt * 16 + l15) * DD + kk * 32 + quad * 8);
            }
            acc[jt] = __builtin_amdgcn_mfma_f32_16x16x32_bf16(afr[kk], bfr, acc[jt], 0, 0, 0);
        }
    }
}

__global__ __launch_bounds__(256) void k_gemm(const void* __restrict__ x,
                                              const void* __restrict__ W,
                                              const void* __restrict__ att_src,
                                              const void* __restrict__ att_dst,
                                              const int* __restrict__ flags,
                                              __hip_bfloat16* __restrict__ h,
                                              float* __restrict__ asrc, float* __restrict__ adst) {
    int f32 = flags[0];
    int wave = threadIdx.x >> 6;
    int lane = threadIdx.x & 63;
    int l15  = lane & 15, quad = lane >> 4;
    long rows_base = (long)blockIdx.x * 64 + wave * 16;

    floatx4 acc[8];
    #pragma unroll
    for (int jt = 0; jt < 8; jt++) acc[jt] = (floatx4){0.f, 0.f, 0.f, 0.f};
    if (f32) gemm_core<1>(x, W, rows_base, l15, quad, acc);
    else     gemm_core<0>(x, W, rows_base, l15, quad, acc);

    float asum[4] = {0.f, 0.f, 0.f, 0.f};
    float dsum[4] = {0.f, 0.f, 0.f, 0.f};
    #pragma unroll
    for (int jt = 0; jt < 8; jt++) {
        int col = jt * 16 + l15;
        float as = ldf(att_src, col, f32);
        float ad = ldf(att_dst, col, f32);
        #pragma unroll
        for (int r = 0; r < 4; r++) {
            float v = acc[jt][r];
            long row = rows_base + quad * 4 + r;
            h[row * DD + col] = __float2bfloat16(v);
            asum[r] += v * as;
            dsum[r] += v * ad;
        }
    }
    #pragma unroll
    for (int r = 0; r < 4; r++) {
        float a = asum[r], d = dsum[r];
        for (int o = 1; o < 16; o <<= 1) { a += __shfl_xor(a, o, 64); d += __shfl_xor(d, o, 64); }
        if (l15 == 0) {
            long row = rows_base + quad * 4 + r;
            asrc[row] = a;
            adst[row] = d;
        }
    }
}

__global__ __launch_bounds__(256) void k_scan(const int* __restrict__ deg, int* __restrict__ offs) {
    __shared__ int part[256];
    int t = threadIdx.x;
    const int PER = (NN + 255) / 256;
    int base = t * PER;
    int s = 0;
    for (int i = 0; i < PER; i++) { int idx = base + i; if (idx < NN) s += deg[idx]; }
    part[t] = s;
    __syncthreads();
    for (int o = 1; o < 256; o <<= 1) {
        int v = (t >= o) ? part[t - o] : 0;
        __syncthreads();
        part[t] += v;
        __syncthreads();
    }
    int run = (t == 0) ? 0 : part[t - 1];
    for (int i = 0; i < PER; i++) {
        int idx = base + i;
        if (idx < NN) { offs[idx] = run; run += deg[idx]; }
    }
    if (t == 255) offs[NN] = run;
}

__global__ __launch_bounds__(256) void k_fill(const int* __restrict__ ei, const int* __restrict__ offs,
                                              const int* __restrict__ flags,
                                              int* __restrict__ cursor, int* __restrict__ eids) {
    int i64 = flags[1];
    int e = blockIdx.x * 256 + threadIdx.x;
    if (e < EE) {
        int d = edst(ei, e, i64);
        int p = atomicAdd(&cursor[d], 1);
        eids[offs[d] + p] = e;
    }
}

__global__ __launch_bounds__(256) void k_main(const int* __restrict__ ei,
                                              const void* __restrict__ attr,
                                              const __hip_bfloat16* __restrict__ h,
                                              const float* __restrict__ asrc,
                                              const float* __restrict__ adst,
                                              const int* __restrict__ deg,
                                              const float* __restrict__ lsum,
                                              const int* __restrict__ offs,
                                              const int* __restrict__ eids,
                                              const float* __restrict__ cptr,
                                              const void* __restrict__ bias,
                                              const int* __restrict__ flags,
                                              void* __restrict__ outbuf) {
    __shared__ int   s_src[4][CAP];
    __shared__ float s_a[4][CAP];
    int f32 = flags[0], i64 = flags[1];
    int wv = threadIdx.x >> 6, lane = threadIdx.x & 63;
    int w = blockIdx.x * 4 + wv;
    int b = w / NN, n = w - b * NN;

    float c  = *cptr;
    int   dg = deg[n];
    int   off = offs[n];
    float an = adst[(long)b * NN + n];
    float lattr = lsum[n] / fmaxf((float)dg, 1.0f);
    int   cnt = dg + 1;
    const float* asrc_b = asrc + (long)b * NN;

    float amax = -INFINITY;
    for (int i = lane; i < cnt; i += 64) {
        int s; float at;
        if (i < dg) { int e = eids[off + i]; s = esrc(ei, e, i64); at = ldf(attr, e, f32); }
        else        { s = n; at = lattr; }
        float a = asrc_b[s] + an + c * at;
        a = (a > 0.f) ? a : SLOPE * a;
        if (i < CAP) { s_src[wv][i] = s; s_a[wv][i] = a; }
        amax = fmaxf(amax, a);
    }
    for (int o = 1; o < 64; o <<= 1) amax = fmaxf(amax, __shfl_xor(amax, o, 64));
    __syncthreads();

    float ssum = 0.f;
    for (int i = lane; i < cnt; i += 64) {
        float a;
        if (i < CAP) a = s_a[wv][i];
        else {
            int s; float at;
            if (i < dg) { int e = eids[off + i]; s = esrc(ei, e, i64); at = ldf(attr, e, f32); }
            else        { s = n; at = lattr; }
            a = asrc_b[s] + an + c * at; a = (a > 0.f) ? a : SLOPE * a;
        }
        float ex = expf(a - amax);
        ssum += ex;
        if (i < CAP) s_a[wv][i] = ex;
    }
    for (int o = 1; o < 64; o <<= 1) ssum += __shfl_xor(ssum, o, 64);
    float inv = 1.0f / (ssum + 1e-16f);
    __syncthreads();

    long attn_base = (long)b * EE2;
    for (int i = lane; i < cnt; i += 64) {
        float ex;
        if (i < CAP) ex = s_a[wv][i];
        else {
            int s; float at;
            if (i < dg) { int e = eids[off + i]; s = esrc(ei, e, i64); at = ldf(attr, e, f32); }
            else        { s = n; at = lattr; }
            float a = asrc_b[s] + an + c * at; a = (a > 0.f) ? a : SLOPE * a;
            ex = expf(a - amax);
        }
        float al = ex * inv;
        if (i < CAP) s_a[wv][i] = al;
        long idx = (i < dg) ? (attn_base + eids[off + i]) : (attn_base + EE + n);
        long gidx = OUT_ELEMS + idx;
        if (f32) ((float*)outbuf)[gidx] = al;
        else     ((__hip_bfloat16*)outbuf)[gidx] = __float2bfloat16(al);
    }
    __syncthreads();

    float acc0 = 0.f, acc1 = 0.f;
    for (int i = 0; i < cnt; i++) {
        int s; float al;
        if (i < CAP) { s = s_src[wv][i]; al = s_a[wv][i]; }
        else {
            float at;
            if (i < dg) { int e = eids[off + i]; s = esrc(ei, e, i64); at = ldf(attr, e, f32); }
            else        { s = n; at = lattr; }
            float a = asrc_b[s] + an + c * at; a = (a > 0.f) ? a : SLOPE * a;
            al = expf(a - amax) * inv;
        }
        const __hip_bfloat162* hr2 = (const __hip_bfloat162*)(h + ((long)b * NN + s) * DD);
        __hip_bfloat162 v = hr2[lane];
        acc0 += al * __bfloat162float(v.x);
        acc1 += al * __bfloat162float(v.y);
    }
    acc0 += ldf(bias, 2 * lane, f32);
    acc1 += ldf(bias, 2 * lane + 1, f32);
    long oidx = ((long)b * NN + n) * 64 + lane;
    if (f32) {
        float2 o2; o2.x = acc0; o2.y = acc1;
        ((float2*)outbuf)[oidx] = o2;
    } else {
        __hip_bfloat162 o;
        o.x = __float2bfloat16(acc0);
        o.y = __float2bfloat16(acc1);
        ((__hip_bfloat162*)outbuf)[oidx] = o;
    }
}

extern "C" void kernel_launch(void* const* d_in, const int* in_sizes, int n_in,
                              void* d_out, int out_size, void* d_ws, size_t ws_size,
                              hipStream_t stream) {
    const void* x        = d_in[0];
    const int*  ei       = (const int*)d_in[1];
    const void* attr     = d_in[2];
    const void* W        = d_in[3];
    const void* We       = d_in[4];
    const void* att_src  = d_in[5];
    const void* att_dst  = d_in[6];
    const void* att_edge = d_in[7];
    const void* bias     = d_in[8];

    char* ws = (char*)d_ws;
    size_t off = 0;
    auto alloc = [&](size_t bytes) { size_t o = off; off = (off + bytes + 255) & ~(size_t)255; return o; };
    __hip_bfloat16* h    = (__hip_bfloat16*)(ws + alloc((size_t)BATCH * NN * DD * 2));
    float* asrc          = (float*)(ws + alloc((size_t)BATCH * NN * 4));
    float* adst          = (float*)(ws + alloc((size_t)BATCH * NN * 4));
    int*   deg           = (int*)  (ws + alloc((size_t)NN * 4));
    float* lsum          = (float*)(ws + alloc((size_t)NN * 4));
    int*   offs          = (int*)  (ws + alloc((size_t)(NN + 1) * 4));
    int*   cursor        = (int*)  (ws + alloc((size_t)NN * 4));
    int*   eids          = (int*)  (ws + alloc((size_t)EE * 4));
    float* cscal         = (float*)(ws + alloc(256));
    int*   flags         = (int*)  (ws + alloc(256));

    hipMemsetAsync(deg,    0, (size_t)NN * 4, stream);
    hipMemsetAsync(lsum,   0, (size_t)NN * 4, stream);
    hipMemsetAsync(cursor, 0, (size_t)NN * 4, stream);

    k_detect<<<1, 256, 0, stream>>>((const unsigned short*)x, ei, flags);
    k_c   <<<1, 64, 0, stream>>>(We, att_edge, flags, cscal);
    k_deg <<<(EE + 255) / 256, 256, 0, stream>>>(ei, attr, flags, deg, lsum);
    k_gemm<<<(BATCH * NN) / 64, 256, 0, stream>>>(x, W, att_src, att_dst, flags, h, asrc, adst);
    k_scan<<<1, 256, 0, stream>>>(deg, offs);
    k_fill<<<(EE + 255) / 256, 256, 0, stream>>>(ei, offs, flags, cursor, eids);
    k_main<<<(BATCH * NN) / 4, 256, 0, stream>>>(ei, attr, h, asrc, adst, deg, lsum,
                                                 offs, eids, cscal, bias, flags, d_out);
}